// Round 19
// baseline (123.051 us; speedup 1.0000x reference)
//
#include <hip/hip_runtime.h>

#define IMG_H 512
#define IMG_W 512
#define IMGSZ (IMG_H * IMG_W)
#define NIMG 48                       // B*C
#define NB 16
#define NPOS 4096
#define DNPIX 12582912.0              // 48*512*512

// Band-streaming SSIM config (r4 structure: LDS vrow, 2 cols/thread)
#define BH 16                         // output rows per block band
#define NBANDS (IMG_H / BH)           // 32
#define SSIM_BLOCKS (NIMG * NBANDS)   // 1536
#define TOTAL_BLOCKS SSIM_BLOCKS
#define WPB 4                         // 256 threads = 4 waves
#define VROW_P 544                    // physical row length after pad-32 swizzle

// pad-every-32 swizzle: stride-2 column access becomes 2-way (free) not 4-way
__device__ __forceinline__ int phys(int i) { return i + (i >> 5); }

__global__ __launch_bounds__(256) void fused_kernel(
    const float* __restrict__ pred, const float* __restrict__ targ,
    const int* __restrict__ pos32, const float* __restrict__ imp,
    double* __restrict__ acc, unsigned int* __restrict__ cnt,
    float* __restrict__ out)
{
    __shared__ float vrow[4][VROW_P];
    __shared__ float red[3][WPB];

    const int tid = threadIdx.x;
    const int lane = tid & 63;
    const int wid = tid >> 6;
    const int bid = blockIdx.x;

    // NO XCD swizzle: natural order keeps vertically-adjacent bands (which
    // share 10 halo rows) on the same/nearby XCD L2 (r4 behavior, 87 us).
    int s = bid;
    const int img = s >> 5;            // NBANDS == 32
    const int band = s & 31;
    const int row0 = band * BH;
    const float* __restrict__ pimg = pred + (size_t)img * IMGSZ;
    const float* __restrict__ timg = targ + (size_t)img * IMGSZ;
    const int c0 = 2 * tid;            // this thread owns columns c0, c0+1

    // zero LDS once (edge/pad columns stay zero forever)
    float* vflat = &vrow[0][0];
    for (int i = tid; i < 4 * VROW_P; i += 256) vflat[i] = 0.f;
    __syncthreads();

    // vertical running sums (11 rows) for col c0 (v*) and c0+1 (w*):
    // x, y, x^2+y^2 (merged), xy
    float vx = 0.f, vy = 0.f, v2 = 0.f, vxy = 0.f;
    float wx = 0.f, wy = 0.f, w2 = 0.f, wxy = 0.f;
    float perc = 0.f, ssim_s = 0.f, samp = 0.f;

    // ---- warm-up: rows row0-5 .. row0+5 ----
    for (int k = 0; k < 11; ++k) {
        int gr = row0 - 5 + k;
        float2 xv = make_float2(0.f, 0.f), yv = make_float2(0.f, 0.f);
        if (gr >= 0 && gr < IMG_H) {
            xv = *(const float2*)(pimg + gr * IMG_W + c0);
            yv = *(const float2*)(timg + gr * IMG_W + c0);
            if (gr >= row0)   // in-band part of warm-up (gr <= row0+5 < row0+BH)
                perc += fabsf(xv.x - yv.x) + fabsf(xv.y - yv.y);
        }
        vx += xv.x; vy += yv.x;
        v2 = fmaf(xv.x, xv.x, fmaf(yv.x, yv.x, v2));
        vxy = fmaf(xv.x, yv.x, vxy);
        wx += xv.y; wy += yv.y;
        w2 = fmaf(xv.y, xv.y, fmaf(yv.y, yv.y, w2));
        wxy = fmaf(xv.y, yv.y, wxy);
    }

    const float inv121 = 1.0f / 121.0f;
    const float inv121x2 = 2.0f / 121.0f;
    const float C1c = 1e-4f, CC = 1e-4f + 9e-4f;   // C1, C1+C2

    // ---- stream down the band ----
    for (int r = 0; r < BH; ++r) {
        if (r > 0) {
            int ge = row0 + r + 5;   // entering row (>= row0+6 > 0)
            int gl = row0 + r - 6;   // leaving row  (<= row0+BH-7 < IMG_H)
            float2 xe = make_float2(0.f, 0.f), ye = make_float2(0.f, 0.f);
            float2 xl = make_float2(0.f, 0.f), yl = make_float2(0.f, 0.f);
            if (ge < IMG_H) {
                xe = *(const float2*)(pimg + ge * IMG_W + c0);
                ye = *(const float2*)(timg + ge * IMG_W + c0);
                if (ge < row0 + BH)   // entering row inside this band
                    perc += fabsf(xe.x - ye.x) + fabsf(xe.y - ye.y);
            }
            if (gl >= 0) {
                xl = *(const float2*)(pimg + gl * IMG_W + c0);
                yl = *(const float2*)(timg + gl * IMG_W + c0);
            }
            vx += xe.x - xl.x;
            vy += ye.x - yl.x;
            v2 += fmaf(xe.x, xe.x, fmaf(ye.x, ye.x,
                  -fmaf(xl.x, xl.x, yl.x * yl.x)));
            vxy = fmaf(-xl.x, yl.x, fmaf(xe.x, ye.x, vxy));
            wx += xe.y - xl.y;
            wy += ye.y - yl.y;
            w2 += fmaf(xe.y, xe.y, fmaf(ye.y, ye.y,
                  -fmaf(xl.y, xl.y, yl.y * yl.y)));
            wxy = fmaf(-xl.y, yl.y, fmaf(xe.y, ye.y, wxy));
        }

        // publish vertical sums for this output row
        int p0 = phys(6 + c0), p1 = phys(6 + c0 + 1);
        vrow[0][p0] = vx;  vrow[0][p1] = wx;
        vrow[1][p0] = vy;  vrow[1][p1] = wy;
        vrow[2][p0] = v2;  vrow[2][p1] = w2;
        vrow[3][p0] = vxy; vrow[3][p1] = wxy;
        __syncthreads();

        // horizontal 11-tap for col c0, then slide to c0+1
        float Sx = 0.f, Sy = 0.f, S2 = 0.f, Sxy = 0.f;
        int base = 6 + c0 - 5;
#pragma unroll
        for (int dx = 0; dx < 11; ++dx) {
            int pi = phys(base + dx);
            Sx  += vrow[0][pi];
            Sy  += vrow[1][pi];
            S2  += vrow[2][pi];
            Sxy += vrow[3][pi];
        }
        {
            float mux = Sx * inv121, muy = Sy * inv121;
            float den1 = fmaf(mux, mux, fmaf(muy, muy, C1c));
            float num1 = fmaf(mux + mux, muy, C1c);
            float den2 = fmaf(S2, inv121, CC - den1);
            float num2 = fmaf(Sxy, inv121x2, CC - num1);
            ssim_s += __fdividef(num1 * num2, den1 * den2);
        }
        int pa = phys(6 + c0 + 6), ps = phys(6 + c0 - 5);
        Sx  += vrow[0][pa] - vrow[0][ps];
        Sy  += vrow[1][pa] - vrow[1][ps];
        S2  += vrow[2][pa] - vrow[2][ps];
        Sxy += vrow[3][pa] - vrow[3][ps];
        {
            float mux = Sx * inv121, muy = Sy * inv121;
            float den1 = fmaf(mux, mux, fmaf(muy, muy, C1c));
            float num1 = fmaf(mux + mux, muy, C1c);
            float den2 = fmaf(S2, inv121, CC - den1);
            float num2 = fmaf(Sxy, inv121x2, CC - num1);
            ssim_s += __fdividef(num1 * num2, den1 * den2);
        }
        __syncthreads();   // WAR: next row overwrites vrow
    }

    // ---------------- sampled loss, spread over all blocks/waves ----------
    // block bid owns samples [bid*NPOS/1536, (bid+1)*NPOS/1536) — 2 or 3;
    // wave w handles one; 64 lanes cooperate (48 pixels + 16 weights).
    {
        int n0 = (bid * NPOS) / SSIM_BLOCKS;
        int n1 = ((bid + 1) * NPOS) / SSIM_BLOCKS;
        // layout probe once: first 64 odd 32-bit words all zero <=> int64
        unsigned long long ball = __ballot(pos32[2 * lane + 1] != 0);
        for (int n = n0 + wid; n < n1; n += WPB) {
            int u, v;
            if (ball == 0ull) { u = pos32[4 * n]; v = pos32[4 * n + 2]; }
            else              { u = pos32[2 * n]; v = pos32[2 * n + 1]; }
            int off = u * IMG_W + v;
            float a = 0.f, w = 0.f;
            if (lane < NIMG) {
                float d = pred[(size_t)lane * IMGSZ + off]
                        - targ[(size_t)lane * IMGSZ + off];
                a = d * d;
            } else {
                w = 1.0f / (imp[(size_t)(lane - NIMG) * IMGSZ + off] + 0.1f);
            }
#pragma unroll
            for (int o = 32; o > 0; o >>= 1) {
                a += __shfl_down(a, o);
                w += __shfl_down(w, o);
            }
            if (lane == 0)
                samp += (w * (1.0f / 16.0f)) * (a * (1.0f / 48.0f));
        }
    }

    // ---------------- reduction: wave -> block -> atomics ----------------
#pragma unroll
    for (int o = 32; o > 0; o >>= 1) {
        ssim_s += __shfl_down(ssim_s, o);
        perc   += __shfl_down(perc, o);
    }
    if (lane == 0) { red[0][wid] = ssim_s; red[1][wid] = perc; red[2][wid] = samp; }
    __syncthreads();
    if (tid == 0) {
        float ss = 0.f, pp = 0.f, mm = 0.f;
#pragma unroll
        for (int k = 0; k < WPB; ++k) {
            ss += red[0][k]; pp += red[1][k]; mm += red[2][k];
        }
        atomicAdd(&acc[0], (double)ss);
        atomicAdd(&acc[1], (double)pp);
        atomicAdd(&acc[2], (double)mm);
        __threadfence();
        unsigned int old = atomicAdd(cnt, 1u);
        if (old == TOTAL_BLOCKS - 1) {
            double s0 = atomicAdd(&acc[0], 0.0);
            double s1 = atomicAdd(&acc[1], 0.0);
            double s2 = atomicAdd(&acc[2], 0.0);
            double sampled = s2 / (double)NPOS;
            double perceptual = s1 / DNPIX;
            double structural = 1.0 - s0 / DNPIX;
            double total = 0.3 * sampled + 0.4 * perceptual + 0.2 * structural;
            out[0] = (float)total;
            out[1] = (float)sampled;
            out[2] = (float)perceptual;
            out[3] = (float)structural;
            out[4] = 0.0f;
        }
    }
}

extern "C" void kernel_launch(void* const* d_in, const int* in_sizes, int n_in,
                              void* d_out, int out_size, void* d_ws, size_t ws_size,
                              hipStream_t stream)
{
    const float* pred = (const float*)d_in[0];
    const float* targ = (const float*)d_in[1];
    const int* pos = (const int*)d_in[2];
    const float* imp = (const float*)d_in[3];
    float* out = (float*)d_out;
    double* acc = (double*)d_ws;                       // acc[0..2]
    unsigned int* cnt = (unsigned int*)((char*)d_ws + 24);

    hipMemsetAsync(d_ws, 0, 32, stream);
    hipLaunchKernelGGL(fused_kernel, dim3(TOTAL_BLOCKS), dim3(256), 0, stream,
                       pred, targ, pos, imp, acc, cnt, out);
}

// Round 20
// 98.012 us; speedup vs baseline: 1.2555x; 1.2555x over previous
//
#include <hip/hip_runtime.h>

#define IMG_H 512
#define IMG_W 512
#define IMGSZ (IMG_H * IMG_W)
#define NIMG 48                       // B*C
#define NB 16
#define NPOS 4096
#define DNPIX 12582912.0              // 48*512*512

#define RB 8                          // rows per band (one wave per band)
#define WPB 4                         // waves per block, vertically adjacent
#define BLOCK_ROWS (RB * WPB)         // 32
#define BGRPS (IMG_H / BLOCK_ROWS)    // 16 block-bands per image
#define SSIM_BLOCKS (NIMG * BGRPS)    // 768 = exactly 3 blocks per CU
#define SAMP_BLOCKS 64                // dedicated gather blocks (overlap SSIM)
#define TOTAL_BLOCKS (SSIM_BLOCKS + SAMP_BLOCKS)   // 832

__device__ __forceinline__ void load8(const float* __restrict__ base, float x[8])
{
    const float4* p = (const float4*)base;
    float4 a = p[0], b = p[1];
    x[0] = a.x; x[1] = a.y; x[2] = a.z; x[3] = a.w;
    x[4] = b.x; x[5] = b.y; x[6] = b.z; x[7] = b.w;
}

// Horizontal 11-tap window sums for 4 quantities (Sx, Sy, Sxx+Syy, Sxy)
// across lane-owned 8-col segments via shfl, then SSIM for the 8 output
// columns of this lane. No LDS, no bank conflicts.
__device__ __forceinline__ float horiz_ssim4(const float V[4][8], int lane)
{
    float W[4][8];
#pragma unroll
    for (int q = 0; q < 4; ++q) {
        float A0 = V[q][0];
        float A1 = A0 + V[q][1];
        float A2 = A1 + V[q][2];
        float A3 = A2 + V[q][3];
        float A4 = A3 + V[q][4];
        float A5 = A4 + V[q][5];
        float A6 = A5 + V[q][6];
        float T  = A6 + V[q][7];
        float B1 = T - A0, B2 = T - A1, B3 = T - A2, B4 = T - A3;
        float B5 = T - A4, B6 = T - A5, B7 = T - A6;
        float LB3 = __shfl_up(B3, 1), LB4 = __shfl_up(B4, 1);
        float LB5 = __shfl_up(B5, 1), LB6 = __shfl_up(B6, 1);
        float LB7 = __shfl_up(B7, 1);
        float RA0 = __shfl_down(A0, 1), RA1 = __shfl_down(A1, 1);
        float RA2 = __shfl_down(A2, 1), RA3 = __shfl_down(A3, 1);
        float RA4 = __shfl_down(A4, 1);
        if (lane == 0)  { LB3 = LB4 = LB5 = LB6 = LB7 = 0.f; }  // cols <0 are 0
        if (lane == 63) { RA0 = RA1 = RA2 = RA3 = RA4 = 0.f; }  // cols >=512 are 0
        W[q][0] = LB3 + A5;
        W[q][1] = LB4 + A6;
        W[q][2] = LB5 + T;
        W[q][3] = LB6 + T + RA0;
        W[q][4] = LB7 + T + RA1;
        W[q][5] = T + RA2;
        W[q][6] = B1 + RA3;
        W[q][7] = B2 + RA4;
    }
    const float inv121 = 1.0f / 121.0f;
    const float inv121x2 = 2.0f / 121.0f;
    const float C1c = 1e-4f, CC = 1e-4f + 9e-4f;   // C1, C1+C2
    float s = 0.f;
#pragma unroll
    for (int j = 0; j < 8; ++j) {
        float mux = W[0][j] * inv121;
        float muy = W[1][j] * inv121;
        float den1 = fmaf(mux, mux, fmaf(muy, muy, C1c));   // mux^2+muy^2+C1
        float num1 = fmaf(mux + mux, muy, C1c);             // 2 mux muy + C1
        float den2 = fmaf(W[2][j], inv121, CC - den1);      // sgx+sgy+C2
        float num2 = fmaf(W[3][j], inv121x2, CC - num1);    // 2 sgxy + C2
        s += __fdividef(num1 * num2, den1 * den2);
    }
    return s;
}

__global__ __launch_bounds__(256) void fused_kernel(
    const float* __restrict__ pred, const float* __restrict__ targ,
    const int* __restrict__ pos32, const float* __restrict__ imp,
    double* __restrict__ acc, unsigned int* __restrict__ cnt,
    float* __restrict__ out)
{
    const int tid = threadIdx.x;
    const int lane = tid & 63;
    const int wid = tid >> 6;
    const int bid = blockIdx.x;
    float ssim_s = 0.f, perc = 0.f, samp = 0.f;

    if (bid < SSIM_BLOCKS) {
        // ------------- SSIM + perceptual (every wave owns an 8-row band) ---
        // bijective XCD swizzle: same-XCD blocks cover contiguous bands
        int s = (bid & 7) * (SSIM_BLOCKS / 8) + (bid >> 3);
        const int img = s >> 4;            // BGRPS == 16
        const int bg = s & 15;
        const int rs = bg * BLOCK_ROWS + wid * RB;   // this wave's 8-row band
        const float* __restrict__ pimg = pred + (size_t)img * IMGSZ;
        const float* __restrict__ timg = targ + (size_t)img * IMGSZ;
        const int c0 = lane * 8;

        float V[4][8];
#pragma unroll
        for (int q = 0; q < 4; ++q)
#pragma unroll
            for (int k = 0; k < 8; ++k) V[q][k] = 0.f;

        // ---- pipelined warm-up: rows rs-5 .. rs+5, one row carried ahead --
        float cx[8], cy[8];
        float cm;
        {
            int gr = rs - 5;
            int gc = max(gr, 0);
            cm = (gr == gc) ? 1.f : 0.f;
            load8(pimg + (size_t)gc * IMG_W + c0, cx);
            load8(timg + (size_t)gc * IMG_W + c0, cy);
        }
        for (int kk = 0; kk < 11; ++kk) {
            float m = cm;
            bool pin = (kk >= 5);           // rows rs..rs+5 are in-band
            float xs[8], ys[8];
#pragma unroll
            for (int k = 0; k < 8; ++k) { xs[k] = cx[k] * m; ys[k] = cy[k] * m; }
            // load next row (kk=10 loads rs+6 = entering row for stream r=1)
            int gr2 = rs - 4 + kk;
            int gc2 = min(max(gr2, 0), IMG_H - 1);
            cm = (gr2 == gc2) ? 1.f : 0.f;
            load8(pimg + (size_t)gc2 * IMG_W + c0, cx);
            load8(timg + (size_t)gc2 * IMG_W + c0, cy);
            // consume while loads fly
#pragma unroll
            for (int k = 0; k < 8; ++k) {
                V[0][k] += xs[k];
                V[1][k] += ys[k];
                V[2][k] = fmaf(xs[k], xs[k], fmaf(ys[k], ys[k], V[2][k]));
                V[3][k] = fmaf(xs[k], ys[k], V[3][k]);
                perc += pin ? fabsf(xs[k] - ys[k]) : 0.f;
            }
        }
        // preload leaving row for r=1 (row rs-5)
        float lx[8], ly[8];
        float lm;
        {
            int gl = rs - 5;
            int glc = max(gl, 0);
            lm = (gl == glc) ? 1.f : 0.f;
            load8(pimg + (size_t)glc * IMG_W + c0, lx);
            load8(timg + (size_t)glc * IMG_W + c0, ly);
        }
        ssim_s += horiz_ssim4(V, lane);    // output row rs

        // ---- pipelined stream rows rs+1 .. rs+6 (prefetch for next step) --
        for (int r = 1; r < RB - 1; ++r) {
            float cme = cm, cml = lm;
            bool pin = (r < 3);             // entering rows rs+6, rs+7 in-band
            float ae[8], be[8], al[8], bl[8];
#pragma unroll
            for (int k = 0; k < 8; ++k) {
                ae[k] = cx[k] * cme; be[k] = cy[k] * cme;
                al[k] = lx[k] * cml; bl[k] = ly[k] * cml;
            }
            // issue next step's loads (rows for step r+1)
            int ge2 = rs + r + 6, gl2 = rs + r - 5;
            int gec = min(ge2, IMG_H - 1);
            int glc = max(gl2, 0);
            cm = (ge2 == gec) ? 1.f : 0.f;
            lm = (gl2 == glc) ? 1.f : 0.f;
            load8(pimg + (size_t)gec * IMG_W + c0, cx);
            load8(timg + (size_t)gec * IMG_W + c0, cy);
            load8(pimg + (size_t)glc * IMG_W + c0, lx);
            load8(timg + (size_t)glc * IMG_W + c0, ly);
            // V-update + perc on entering in-band rows
#pragma unroll
            for (int k = 0; k < 8; ++k) {
                V[0][k] += ae[k] - al[k];
                V[1][k] += be[k] - bl[k];
                V[2][k] += fmaf(ae[k], ae[k], fmaf(be[k], be[k],
                           -fmaf(al[k], al[k], bl[k] * bl[k])));
                V[3][k] += fmaf(ae[k], be[k], -al[k] * bl[k]);
                perc += pin ? fabsf(ae[k] - be[k]) : 0.f;
            }
            ssim_s += horiz_ssim4(V, lane); // output row rs+r
        }
        // ---- peeled final step r = RB-1: consume only, no dummy loads ----
        {
#pragma unroll
            for (int k = 0; k < 8; ++k) {
                float a = cx[k] * cm, b = cy[k] * cm;
                float c = lx[k] * lm, d = ly[k] * lm;
                V[0][k] += a - c;
                V[1][k] += b - d;
                V[2][k] += fmaf(a, a, fmaf(b, b, -fmaf(c, c, d * d)));
                V[3][k] += fmaf(a, b, -c * d);
            }
            ssim_s += horiz_ssim4(V, lane); // output row rs+RB-1
        }
    } else {
        // ------------- sampled loss: dedicated blocks, overlap SSIM -------
        // 64 blocks x 4 waves x 16 samples = 4096; iterations independent
        // so gathers pipeline (multiple in flight per wave).
        int sb = bid - SSIM_BLOCKS;        // 0..63
        // layout probe once: first 64 odd 32-bit words all zero <=> int64
        unsigned long long ball = __ballot(pos32[2 * lane + 1] != 0);
        int nbase = (sb * WPB + wid) * 16;
        for (int i = 0; i < 16; ++i) {
            int n = nbase + i;
            int u, v;
            if (ball == 0ull) { u = pos32[4 * n]; v = pos32[4 * n + 2]; }
            else              { u = pos32[2 * n]; v = pos32[2 * n + 1]; }
            int off = u * IMG_W + v;
            float a = 0.f, w = 0.f;
            if (lane < NIMG) {
                float d = pred[(size_t)lane * IMGSZ + off]
                        - targ[(size_t)lane * IMGSZ + off];
                a = d * d;
            } else {
                w = 1.0f / (imp[(size_t)(lane - NIMG) * IMGSZ + off] + 0.1f);
            }
#pragma unroll
            for (int o = 32; o > 0; o >>= 1) {
                a += __shfl_down(a, o);
                w += __shfl_down(w, o);
            }
            if (lane == 0)
                samp += (w * (1.0f / 16.0f)) * (a * (1.0f / 48.0f));
        }
    }

    // ---------------- reduction: wave -> block -> atomics ----------------
#pragma unroll
    for (int o = 32; o > 0; o >>= 1) {
        ssim_s += __shfl_down(ssim_s, o);
        perc   += __shfl_down(perc, o);
    }
    __shared__ float red[3][WPB];
    if (lane == 0) { red[0][wid] = ssim_s; red[1][wid] = perc; red[2][wid] = samp; }
    __syncthreads();
    if (tid == 0) {
        float ss = 0.f, pp = 0.f, mm = 0.f;
#pragma unroll
        for (int k = 0; k < WPB; ++k) {
            ss += red[0][k]; pp += red[1][k]; mm += red[2][k];
        }
        atomicAdd(&acc[0], (double)ss);
        atomicAdd(&acc[1], (double)pp);
        atomicAdd(&acc[2], (double)mm);
        __threadfence();
        unsigned int old = atomicAdd(cnt, 1u);
        if (old == TOTAL_BLOCKS - 1) {
            double s0 = atomicAdd(&acc[0], 0.0);
            double s1 = atomicAdd(&acc[1], 0.0);
            double s2 = atomicAdd(&acc[2], 0.0);
            double sampled = s2 / (double)NPOS;
            double perceptual = s1 / DNPIX;
            double structural = 1.0 - s0 / DNPIX;
            double total = 0.3 * sampled + 0.4 * perceptual + 0.2 * structural;
            out[0] = (float)total;
            out[1] = (float)sampled;
            out[2] = (float)perceptual;
            out[3] = (float)structural;
            out[4] = 0.0f;
        }
    }
}

extern "C" void kernel_launch(void* const* d_in, const int* in_sizes, int n_in,
                              void* d_out, int out_size, void* d_ws, size_t ws_size,
                              hipStream_t stream)
{
    const float* pred = (const float*)d_in[0];
    const float* targ = (const float*)d_in[1];
    const int* pos = (const int*)d_in[2];
    const float* imp = (const float*)d_in[3];
    float* out = (float*)d_out;
    double* acc = (double*)d_ws;                       // acc[0..2]
    unsigned int* cnt = (unsigned int*)((char*)d_ws + 24);

    hipMemsetAsync(d_ws, 0, 32, stream);
    hipLaunchKernelGGL(fused_kernel, dim3(TOTAL_BLOCKS), dim3(256), 0, stream,
                       pred, targ, pos, imp, acc, cnt, out);
}

// Round 24
// 89.959 us; speedup vs baseline: 1.3679x; 1.0895x over previous
//
#include <hip/hip_runtime.h>

#define IMG_H 512
#define IMG_W 512
#define IMGSZ (IMG_H * IMG_W)
#define NIMG 48                       // B*C
#define NB 16
#define NPOS 4096
#define DNPIX 12582912.0              // 48*512*512

#define RB 8                          // rows per band (one wave per band)
#define WPB 4                         // waves per block, vertically adjacent
#define BLOCK_ROWS (RB * WPB)         // 32
#define BGRPS (IMG_H / BLOCK_ROWS)    // 16 block-bands per image
#define SSIM_BLOCKS (NIMG * BGRPS)    // 768 = exactly 3 blocks per CU
#define TOTAL_BLOCKS SSIM_BLOCKS

__device__ __forceinline__ void load8(const float* __restrict__ base, float x[8])
{
    const float4* p = (const float4*)base;
    float4 a = p[0], b = p[1];
    x[0] = a.x; x[1] = a.y; x[2] = a.z; x[3] = a.w;
    x[4] = b.x; x[5] = b.y; x[6] = b.z; x[7] = b.w;
}

// Horizontal 11-tap window sums for 4 quantities (Sx, Sy, Sxx+Syy, Sxy)
// across lane-owned 8-col segments via shfl, then SSIM for the 8 output
// columns of this lane. No LDS, no bank conflicts.
__device__ __forceinline__ float horiz_ssim4(const float V[4][8], int lane)
{
    float W[4][8];
#pragma unroll
    for (int q = 0; q < 4; ++q) {
        float A0 = V[q][0];
        float A1 = A0 + V[q][1];
        float A2 = A1 + V[q][2];
        float A3 = A2 + V[q][3];
        float A4 = A3 + V[q][4];
        float A5 = A4 + V[q][5];
        float A6 = A5 + V[q][6];
        float T  = A6 + V[q][7];
        float B1 = T - A0, B2 = T - A1, B3 = T - A2, B4 = T - A3;
        float B5 = T - A4, B6 = T - A5, B7 = T - A6;
        float LB3 = __shfl_up(B3, 1), LB4 = __shfl_up(B4, 1);
        float LB5 = __shfl_up(B5, 1), LB6 = __shfl_up(B6, 1);
        float LB7 = __shfl_up(B7, 1);
        float RA0 = __shfl_down(A0, 1), RA1 = __shfl_down(A1, 1);
        float RA2 = __shfl_down(A2, 1), RA3 = __shfl_down(A3, 1);
        float RA4 = __shfl_down(A4, 1);
        if (lane == 0)  { LB3 = LB4 = LB5 = LB6 = LB7 = 0.f; }  // cols <0 are 0
        if (lane == 63) { RA0 = RA1 = RA2 = RA3 = RA4 = 0.f; }  // cols >=512 are 0
        W[q][0] = LB3 + A5;
        W[q][1] = LB4 + A6;
        W[q][2] = LB5 + T;
        W[q][3] = LB6 + T + RA0;
        W[q][4] = LB7 + T + RA1;
        W[q][5] = T + RA2;
        W[q][6] = B1 + RA3;
        W[q][7] = B2 + RA4;
    }
    const float inv121 = 1.0f / 121.0f;
    const float inv121x2 = 2.0f / 121.0f;
    const float C1c = 1e-4f, CC = 1e-4f + 9e-4f;   // C1, C1+C2
    float s = 0.f;
#pragma unroll
    for (int j = 0; j < 8; ++j) {
        float mux = W[0][j] * inv121;
        float muy = W[1][j] * inv121;
        float den1 = fmaf(mux, mux, fmaf(muy, muy, C1c));   // mux^2+muy^2+C1
        float num1 = fmaf(mux + mux, muy, C1c);             // 2 mux muy + C1
        float den2 = fmaf(W[2][j], inv121, CC - den1);      // sgx+sgy+C2
        float num2 = fmaf(W[3][j], inv121x2, CC - num1);    // 2 sgxy + C2
        s += __fdividef(num1 * num2, den1 * den2);
    }
    return s;
}

__global__ __launch_bounds__(256) void fused_kernel(
    const float* __restrict__ pred, const float* __restrict__ targ,
    const int* __restrict__ pos32, const float* __restrict__ imp,
    double* __restrict__ acc, unsigned int* __restrict__ cnt,
    float* __restrict__ out)
{
    const int tid = threadIdx.x;
    const int lane = tid & 63;
    const int wid = tid >> 6;
    const int bid = blockIdx.x;
    float ssim_s = 0.f, perc = 0.f, samp = 0.f;

    // ---------------- SSIM + perceptual (every wave owns an 8-row band) ----
    // bijective XCD swizzle: same-XCD blocks cover contiguous bands
    int s = (bid & 7) * (SSIM_BLOCKS / 8) + (bid >> 3);
    const int img = s >> 4;            // BGRPS == 16
    const int bg = s & 15;
    const int rs = bg * BLOCK_ROWS + wid * RB;   // this wave's 8-row band
    const float* __restrict__ pimg = pred + (size_t)img * IMGSZ;
    const float* __restrict__ timg = targ + (size_t)img * IMGSZ;
    const int c0 = lane * 8;

    float V[4][8];
#pragma unroll
    for (int q = 0; q < 4; ++q)
#pragma unroll
        for (int k = 0; k < 8; ++k) V[q][k] = 0.f;

    // ---- pipelined warm-up: rows rs-5 .. rs+5, one row carried ahead ----
    float cx[8], cy[8];
    float cm;
    {
        int gr = rs - 5;
        int gc = max(gr, 0);
        cm = (gr == gc) ? 1.f : 0.f;
        load8(pimg + (size_t)gc * IMG_W + c0, cx);
        load8(timg + (size_t)gc * IMG_W + c0, cy);
    }
    for (int kk = 0; kk < 11; ++kk) {
        float m = cm;
        bool pin = (kk >= 5);           // rows rs..rs+5 are in-band
        float xs[8], ys[8];
#pragma unroll
        for (int k = 0; k < 8; ++k) { xs[k] = cx[k] * m; ys[k] = cy[k] * m; }
        // load next row (kk=10 loads rs+6 = entering row for stream step 1)
        int gr2 = rs - 4 + kk;
        int gc2 = min(max(gr2, 0), IMG_H - 1);
        cm = (gr2 == gc2) ? 1.f : 0.f;
        load8(pimg + (size_t)gc2 * IMG_W + c0, cx);
        load8(timg + (size_t)gc2 * IMG_W + c0, cy);
        // consume while loads fly
#pragma unroll
        for (int k = 0; k < 8; ++k) {
            V[0][k] += xs[k];
            V[1][k] += ys[k];
            V[2][k] = fmaf(xs[k], xs[k], fmaf(ys[k], ys[k], V[2][k]));
            V[3][k] = fmaf(xs[k], ys[k], V[3][k]);
            perc += pin ? fabsf(xs[k] - ys[k]) : 0.f;
        }
    }
    // preload leaving row for r=1 (row rs-5)
    float lx[8], ly[8];
    float lm;
    {
        int gl = rs - 5;
        int glc = max(gl, 0);
        lm = (gl == glc) ? 1.f : 0.f;
        load8(pimg + (size_t)glc * IMG_W + c0, lx);
        load8(timg + (size_t)glc * IMG_W + c0, ly);
    }
    ssim_s += horiz_ssim4(V, lane);    // output row rs

    // ---- pipelined stream: rows rs+1 .. rs+7 ----
    for (int r = 1; r < RB; ++r) {
        float cme = cm, cml = lm;
        bool pin = (r < 3);             // entering rows rs+6, rs+7 are in-band
        float ae[8], be[8], al[8], bl[8];
#pragma unroll
        for (int k = 0; k < 8; ++k) {
            ae[k] = cx[k] * cme; be[k] = cy[k] * cme;
            al[k] = lx[k] * cml; bl[k] = ly[k] * cml;
        }
        // issue next step's loads (dummy-clamped at r == RB-1)
        int ge2 = rs + r + 6;           // entering row for r+1
        int gl2 = rs + r - 5;           // leaving row for r+1
        int gec = min(ge2, IMG_H - 1);  // ge2 >= 7 > 0
        int glc = max(gl2, 0);          // gl2 <= 506 < 512
        cm = (ge2 == gec) ? 1.f : 0.f;
        lm = (gl2 == glc) ? 1.f : 0.f;
        load8(pimg + (size_t)gec * IMG_W + c0, cx);
        load8(timg + (size_t)gec * IMG_W + c0, cy);
        load8(pimg + (size_t)glc * IMG_W + c0, lx);
        load8(timg + (size_t)glc * IMG_W + c0, ly);
        // V-update + perc on entering in-band rows
#pragma unroll
        for (int k = 0; k < 8; ++k) {
            V[0][k] += ae[k] - al[k];
            V[1][k] += be[k] - bl[k];
            V[2][k] += fmaf(ae[k], ae[k], fmaf(be[k], be[k],
                       -fmaf(al[k], al[k], bl[k] * bl[k])));
            V[3][k] += fmaf(ae[k], be[k], -al[k] * bl[k]);
            perc += pin ? fabsf(ae[k] - be[k]) : 0.f;
        }
        ssim_s += horiz_ssim4(V, lane); // output row rs+r
    }

    // ---------------- sampled loss, spread over all blocks/waves ----------
    // block bid owns samples [bid*NPOS/768, (bid+1)*NPOS/768) — 5 or 6;
    // wave w handles samples n0+w, n0+w+4, ...; 64 lanes cooperate on one.
    {
        int n0 = (bid * NPOS) / SSIM_BLOCKS;
        int n1 = ((bid + 1) * NPOS) / SSIM_BLOCKS;
        // layout probe once: first 64 odd 32-bit words all zero <=> int64
        unsigned long long ball = __ballot(pos32[2 * lane + 1] != 0);
        for (int n = n0 + wid; n < n1; n += WPB) {
            int u, v;
            if (ball == 0ull) { u = pos32[4 * n]; v = pos32[4 * n + 2]; }
            else              { u = pos32[2 * n]; v = pos32[2 * n + 1]; }
            int off = u * IMG_W + v;
            float a = 0.f, w = 0.f;
            if (lane < NIMG) {
                float d = pred[(size_t)lane * IMGSZ + off]
                        - targ[(size_t)lane * IMGSZ + off];
                a = d * d;
            } else {
                w = 1.0f / (imp[(size_t)(lane - NIMG) * IMGSZ + off] + 0.1f);
            }
#pragma unroll
            for (int o = 32; o > 0; o >>= 1) {
                a += __shfl_down(a, o);
                w += __shfl_down(w, o);
            }
            if (lane == 0)
                samp += (w * (1.0f / 16.0f)) * (a * (1.0f / 48.0f));
        }
    }

    // ---------------- reduction: wave -> block -> atomics ----------------
#pragma unroll
    for (int o = 32; o > 0; o >>= 1) {
        ssim_s += __shfl_down(ssim_s, o);
        perc   += __shfl_down(perc, o);
    }
    __shared__ float red[3][WPB];
    if (lane == 0) { red[0][wid] = ssim_s; red[1][wid] = perc; red[2][wid] = samp; }
    __syncthreads();
    if (tid == 0) {
        float ss = 0.f, pp = 0.f, mm = 0.f;
#pragma unroll
        for (int k = 0; k < WPB; ++k) {
            ss += red[0][k]; pp += red[1][k]; mm += red[2][k];
        }
        atomicAdd(&acc[0], (double)ss);
        atomicAdd(&acc[1], (double)pp);
        atomicAdd(&acc[2], (double)mm);
        __threadfence();
        unsigned int old = atomicAdd(cnt, 1u);
        if (old == TOTAL_BLOCKS - 1) {
            double s0 = atomicAdd(&acc[0], 0.0);
            double s1 = atomicAdd(&acc[1], 0.0);
            double s2 = atomicAdd(&acc[2], 0.0);
            double sampled = s2 / (double)NPOS;
            double perceptual = s1 / DNPIX;
            double structural = 1.0 - s0 / DNPIX;
            double total = 0.3 * sampled + 0.4 * perceptual + 0.2 * structural;
            out[0] = (float)total;
            out[1] = (float)sampled;
            out[2] = (float)perceptual;
            out[3] = (float)structural;
            out[4] = 0.0f;
        }
    }
}

extern "C" void kernel_launch(void* const* d_in, const int* in_sizes, int n_in,
                              void* d_out, int out_size, void* d_ws, size_t ws_size,
                              hipStream_t stream)
{
    const float* pred = (const float*)d_in[0];
    const float* targ = (const float*)d_in[1];
    const int* pos = (const int*)d_in[2];
    const float* imp = (const float*)d_in[3];
    float* out = (float*)d_out;
    double* acc = (double*)d_ws;                       // acc[0..2]
    unsigned int* cnt = (unsigned int*)((char*)d_ws + 24);

    hipMemsetAsync(d_ws, 0, 32, stream);
    hipLaunchKernelGGL(fused_kernel, dim3(TOTAL_BLOCKS), dim3(256), 0, stream,
                       pred, targ, pos, imp, acc, cnt, out);
}